// Round 11
// baseline (420.383 us; speedup 1.0000x reference)
//
#include <hip/hip_runtime.h>
#include <hip/hip_bf16.h>

#define N 8192
#define DIN 128
#define DHID 256
#define DOUT 64
#define VP 136   // LDS row stride (ushorts) for the 128-wide PV tile

typedef __attribute__((ext_vector_type(8))) short short8;
typedef __attribute__((ext_vector_type(8))) unsigned short u16x8;
typedef __attribute__((ext_vector_type(4))) float f32x4;
typedef __attribute__((ext_vector_type(2))) unsigned long long u64x2;

typedef __attribute__((address_space(1))) const unsigned int GlbU32;
typedef __attribute__((address_space(3))) unsigned int LdsU32;

__device__ inline void gload16(const void* g, void* l) {
  __builtin_amdgcn_global_load_lds((GlbU32*)g, (LdsU32*)l, 16, 0, 0);
}

// lgkmcnt-only barrier: LDS ordering without draining vmcnt (global stores keep flying)
#define LGKM_BAR()                                            \
  do {                                                        \
    asm volatile("s_waitcnt lgkmcnt(0)" ::: "memory");        \
    __builtin_amdgcn_sched_barrier(0);                        \
    __builtin_amdgcn_s_barrier();                             \
    __builtin_amdgcn_sched_barrier(0);                        \
  } while (0)

__device__ inline unsigned short f2bf(float x) {
  unsigned u = __float_as_uint(x);
  u += 0x7FFF + ((u >> 16) & 1);   // RNE
  return (unsigned short)(u >> 16);
}
__device__ inline float bf2f(unsigned short u) {
  return __uint_as_float(((unsigned)u) << 16);
}
__device__ inline float sig_clip(float x) {
  float s = 1.0f / (1.0f + __expf(-x));
  return fmaxf(s, 0.1f);
}

// ---------------- K0: pack (A>0) into interleaved bitmask, 8 MB ----------------
__global__ __launch_bounds__(256) void maskpack(const float* __restrict__ A,
                                                unsigned long long* __restrict__ Mb) {
  size_t i = (size_t)blockIdx.x * 256 + threadIdx.x;
  size_t step = (size_t)gridDim.x * 256;
  int l = threadIdx.x & 63;
  for (; i < (size_t)N * N / 4; i += step) {
    f32x4 a = *(const f32x4*)&A[i * 4];
    unsigned long long b0 = __ballot(a[0] > 0.f);
    unsigned long long b1 = __ballot(a[1] > 0.f);
    unsigned long long b2 = __ballot(a[2] > 0.f);
    unsigned long long b3 = __ballot(a[3] > 0.f);
    size_t g = (i - l) >> 6;
    if (l < 4) {
      unsigned long long bb = (l == 0) ? b0 : (l == 1) ? b1 : (l == 2) ? b2 : b3;
      Mb[g * 4 + l] = bb;
    }
  }
}

// ---------------- K1: BatchNorm statistics ----------------
__global__ void bn_stats(const float* __restrict__ H, const float* __restrict__ bnw,
                         const float* __restrict__ bnb, float* __restrict__ scale,
                         float* __restrict__ shift) {
  int f = blockIdx.x;
  int t = threadIdx.x;
  float s = 0.f, sq = 0.f;
  for (int r = t; r < N; r += 256) {
    float v = H[(size_t)r * DIN + f];
    s += v; sq += v * v;
  }
  __shared__ float ss[256], s2[256];
  ss[t] = s; s2[t] = sq;
  __syncthreads();
  for (int o = 128; o > 0; o >>= 1) {
    if (t < o) { ss[t] += ss[t + o]; s2[t] += s2[t + o]; }
    __syncthreads();
  }
  if (t == 0) {
    float mean = ss[0] * (1.0f / N);
    float var = s2[0] * (1.0f / N) - mean * mean;
    float sc = rsqrtf(var + 1e-5f) * bnw[f];
    scale[f] = sc;
    shift[f] = bnb[f] - mean * sc;
  }
}

// ---------------- K2: Hn -> Hx bf16 [N,256], M2T bf16 [64][N] ----------------
__global__ __launch_bounds__(256) void proj(const float* __restrict__ H,
                     const float* __restrict__ scale, const float* __restrict__ shift,
                     const float* __restrict__ Wt, const float* __restrict__ bt,
                     const float* __restrict__ Wo, const float* __restrict__ bo,
                     unsigned short* __restrict__ Hx, unsigned short* __restrict__ M2T) {
  __shared__ float hn[8][DIN];
  int i0 = blockIdx.x * 8;
  int t = threadIdx.x;
  #pragma unroll
  for (int rep = 0; rep < 4; ++rep) {
    int idx = rep * 256 + t;
    int r = idx >> 7, c = idx & 127;
    float h = H[(size_t)(i0 + r) * DIN + c];
    hn[r][c] = fmaf(h, scale[c], shift[c]);
  }
  __syncthreads();
  {
    int c = t;  // 0..255
    float acc[8];
    float b = bt[c];
    #pragma unroll
    for (int r = 0; r < 8; ++r) acc[r] = b;
    for (int k = 0; k < DIN; ++k) {
      float w = Wt[k * DHID + c];
      #pragma unroll
      for (int r = 0; r < 8; ++r) acc[r] = fmaf(hn[r][k], w, acc[r]);
    }
    #pragma unroll
    for (int r = 0; r < 8; ++r) Hx[(size_t)(i0 + r) * DHID + c] = f2bf(acc[r]);
  }
  if (t < DOUT) {
    int c = t;
    float acc[8];
    float b = bo[c];
    #pragma unroll
    for (int r = 0; r < 8; ++r) acc[r] = b;
    for (int k = 0; k < DIN; ++k) {
      float w = Wo[k * DOUT + c];
      #pragma unroll
      for (int r = 0; r < 8; ++r) acc[r] = fmaf(hn[r][k], w, acc[r]);
    }
    u16x8 v;
    #pragma unroll
    for (int r = 0; r < 8; ++r) v[r] = f2bf(acc[r]);
    *(u16x8*)&M2T[(size_t)c * N + i0] = v;
  }
}

// ---------------- K3: rsum — band structure, full square, rowsums only ----------------
// Block = i-tile x band of 8 j-tiles. A-frags in regs; B-only staging; no stores.
__global__ __launch_bounds__(256) void rsum(const unsigned short* __restrict__ Hx,
                     const unsigned long long* __restrict__ Mb,
                     float* __restrict__ rowsum) {
  __shared__ unsigned short lsh[16384];   // A-init all; steady-state lb = [0,4096)
  __shared__ unsigned mbt32[128][4];
  unsigned short* lb = lsh;
  const int blk = blockIdx.x;
  const int jq = blk & 7;
  const int it = blk >> 3;
  const int i0 = it * 128;
  const int t = threadIdx.x;
  const int w = t >> 6, l = t & 63;
  const int lr = l & 15, lg = l >> 4;
  const int srow = l >> 3;
  const int scol = ((l & 7) ^ srow) * 8;
  const int fswz = (lr & 7) * 8;

  // A-init: stage Hx[i-tile] in 2 halves, extract register fragments
  short8 af[2][8];
  #pragma unroll
  for (int h = 0; h < 2; ++h) {
    __syncthreads();
    #pragma unroll
    for (int itr = 0; itr < 8; ++itr) {
      int idx = itr * 4 + w;
      int c4 = idx >> 3, rg = idx & 7;
      int row = h * 64 + rg * 8 + srow;
      gload16(&Hx[(size_t)(i0 + row) * DHID + c4 * 64 + scol], &lsh[idx * 512]);
    }
    __syncthreads();
    if ((w >> 1) == h) {
      #pragma unroll
      for (int c4 = 0; c4 < 4; ++c4)
        #pragma unroll
        for (int kk = 0; kk < 2; ++kk)
          #pragma unroll
          for (int m = 0; m < 2; ++m)
            af[m][c4 * 2 + kk] = *(const short8*)&lsh[c4 * 4096 +
                ((w & 1) * 32 + m * 16 + lr) * 64 + ((kk * 32 + lg * 8) ^ fswz)];
    }
  }
  __syncthreads();

  // mask prologue (jt=0 of band)
  {
    int j0 = jq * 8 * 128;
    int mrow = t >> 1, ep = (t & 1) * 2;
    u64x2 mv = *(const u64x2*)&Mb[(size_t)(i0 + mrow) * (N / 64) + (j0 >> 8) * 4 + ep];
    int sh = (j0 & 128) ? 32 : 0;
    mbt32[mrow][ep] = (unsigned)(mv[0] >> sh);
    mbt32[mrow][ep + 1] = (unsigned)(mv[1] >> sh);
  }

  float rs[2][4] = {{0.f, 0.f, 0.f, 0.f}, {0.f, 0.f, 0.f, 0.f}};
  f32x4 zero = {0.f, 0.f, 0.f, 0.f};

  for (int jtl = 0; jtl < 8; ++jtl) {
    const int j0 = (jq * 8 + jtl) * 128;
    f32x4 acc[2][8];
    #pragma unroll
    for (int m = 0; m < 2; ++m)
      #pragma unroll
      for (int n = 0; n < 8; ++n) acc[m][n] = zero;

    #pragma unroll
    for (int c4 = 0; c4 < 4; ++c4) {
      __syncthreads();
      #pragma unroll
      for (int itr = 0; itr < 4; ++itr) {
        int rg = itr * 4 + w;
        int row = rg * 8 + srow;
        gload16(&Hx[(size_t)(j0 + row) * DHID + c4 * 64 + scol], &lb[rg * 512]);
      }
      __syncthreads();
      #pragma unroll
      for (int kk = 0; kk < 2; ++kk) {
        int c = (kk * 32 + lg * 8) ^ fswz;
        short8 bf[8];
        #pragma unroll
        for (int n = 0; n < 8; ++n)
          bf[n] = *(const short8*)&lb[(n * 16 + lr) * 64 + c];
        #pragma unroll
        for (int m = 0; m < 2; ++m)
          #pragma unroll
          for (int n = 0; n < 8; ++n)
            acc[m][n] = __builtin_amdgcn_mfma_f32_16x16x32_bf16(af[m][c4 * 2 + kk], bf[n], acc[m][n], 0, 0, 0);
      }
    }

    // epilogue: accumulate row partials (no stores)
    #pragma unroll
    for (int m = 0; m < 2; ++m) {
      #pragma unroll
      for (int r = 0; r < 4; ++r) {
        int rl = w * 32 + m * 16 + lg * 4 + r;
        int gi = i0 + rl;
        unsigned mw = mbt32[rl][lr & 3];
        float part = 0.f;
        #pragma unroll
        for (int n = 0; n < 8; ++n) {
          int gj = j0 + n * 16 + lr;
          float ms = ((mw >> (n * 4 + (lr >> 2))) & 1u) ? 1.f : 0.f;
          part += sig_clip(acc[m][n][r]) * ms + (gi == gj ? 1.f : 0.f);
        }
        rs[m][r] += part;
      }
    }
    // next tile's mask (barrier: all mbt32 reads done before overwrite)
    __syncthreads();
    if (jtl < 7) {
      int nj0 = (jq * 8 + jtl + 1) * 128;
      int mrow = t >> 1, ep = (t & 1) * 2;
      u64x2 mv = *(const u64x2*)&Mb[(size_t)(i0 + mrow) * (N / 64) + (nj0 >> 8) * 4 + ep];
      int sh = (nj0 & 128) ? 32 : 0;
      mbt32[mrow][ep] = (unsigned)(mv[0] >> sh);
      mbt32[mrow][ep + 1] = (unsigned)(mv[1] >> sh);
    }
  }

  // one atomic set per block
  #pragma unroll
  for (int m = 0; m < 2; ++m)
    #pragma unroll
    for (int r = 0; r < 4; ++r) {
      float p = rs[m][r];
      p += __shfl_xor(p, 1);
      p += __shfl_xor(p, 2);
      p += __shfl_xor(p, 4);
      p += __shfl_xor(p, 8);
      if (lr == 0) atomicAdd(&rowsum[i0 + w * 32 + m * 16 + lg * 4 + r], p);
    }
}

// ---------------- K3b: d = rsqrt(rowsum), in place ----------------
__global__ void dfin(float* rs) {
  int i = blockIdx.x * 256 + threadIdx.x;
  if (i < N) rs[i] = rsqrtf(rs[i]);
}

// ---------------- K4: finmm — recompute S, scale, coalesced Ahat write, fused PV ----------------
// Block = i-tile x band of 4 j-tiles (grid 1024). Epilogue writes bf16 LDS tile only;
// Ahat f32 stores come from a coalesced LDS-read pass (512 B/row contiguous).
__global__ __launch_bounds__(256) void finmm(const unsigned short* __restrict__ Hx,
                     const unsigned long long* __restrict__ Mb,
                     const float* __restrict__ dd,
                     const unsigned short* __restrict__ M2T,
                     float* __restrict__ Ahat, float* __restrict__ out) {
  __shared__ unsigned short lsh[21504];  // A-init [0,16384); then lb=[0,4096), lVb=lsh+4096: [128][VP]
  __shared__ unsigned mbt32[128][4];
  unsigned short* lb = lsh;
  unsigned short* lVb = lsh + 4096;
  const int blk = blockIdx.x;
  const int jq = blk & 15;                // 16 bands of 4 tiles
  const int it = blk >> 4;
  const int i0 = it * 128;
  const int t = threadIdx.x;
  const int w = t >> 6, l = t & 63;
  const int lr = l & 15, lg = l >> 4;
  const int srow = l >> 3;
  const int scol = ((l & 7) ^ srow) * 8;
  const int fswz = (lr & 7) * 8;

  // A-init
  short8 af[2][8];
  #pragma unroll
  for (int h = 0; h < 2; ++h) {
    __syncthreads();
    #pragma unroll
    for (int itr = 0; itr < 8; ++itr) {
      int idx = itr * 4 + w;
      int c4 = idx >> 3, rg = idx & 7;
      int row = h * 64 + rg * 8 + srow;
      gload16(&Hx[(size_t)(i0 + row) * DHID + c4 * 64 + scol], &lsh[idx * 512]);
    }
    __syncthreads();
    if ((w >> 1) == h) {
      #pragma unroll
      for (int c4 = 0; c4 < 4; ++c4)
        #pragma unroll
        for (int kk = 0; kk < 2; ++kk)
          #pragma unroll
          for (int m = 0; m < 2; ++m)
            af[m][c4 * 2 + kk] = *(const short8*)&lsh[c4 * 4096 +
                ((w & 1) * 32 + m * 16 + lr) * 64 + ((kk * 32 + lg * 8) ^ fswz)];
    }
  }
  __syncthreads();

  float di[2][4];
  #pragma unroll
  for (int m = 0; m < 2; ++m)
    #pragma unroll
    for (int r = 0; r < 4; ++r)
      di[m][r] = dd[i0 + w * 32 + m * 16 + lg * 4 + r];

  // mask prologue
  {
    int j0 = jq * 4 * 128;
    int mrow = t >> 1, ep = (t & 1) * 2;
    u64x2 mv = *(const u64x2*)&Mb[(size_t)(i0 + mrow) * (N / 64) + (j0 >> 8) * 4 + ep];
    int sh = (j0 & 128) ? 32 : 0;
    mbt32[mrow][ep] = (unsigned)(mv[0] >> sh);
    mbt32[mrow][ep + 1] = (unsigned)(mv[1] >> sh);
  }

  f32x4 acc2[2][4];
  f32x4 zero = {0.f, 0.f, 0.f, 0.f};
  #pragma unroll
  for (int m = 0; m < 2; ++m)
    #pragma unroll
    for (int n = 0; n < 4; ++n) acc2[m][n] = zero;

  for (int jtl = 0; jtl < 4; ++jtl) {
    const int j0 = (jq * 4 + jtl) * 128;
    f32x4 acc[2][8];
    #pragma unroll
    for (int m = 0; m < 2; ++m)
      #pragma unroll
      for (int n = 0; n < 8; ++n) acc[m][n] = zero;

    // QK^T K-loop
    #pragma unroll
    for (int c4 = 0; c4 < 4; ++c4) {
      __syncthreads();
      #pragma unroll
      for (int itr = 0; itr < 4; ++itr) {
        int rg = itr * 4 + w;
        int row = rg * 8 + srow;
        gload16(&Hx[(size_t)(j0 + row) * DHID + c4 * 64 + scol], &lb[rg * 512]);
      }
      __syncthreads();
      #pragma unroll
      for (int kk = 0; kk < 2; ++kk) {
        int c = (kk * 32 + lg * 8) ^ fswz;
        short8 bf[8];
        #pragma unroll
        for (int n = 0; n < 8; ++n)
          bf[n] = *(const short8*)&lb[(n * 16 + lr) * 64 + c];
        #pragma unroll
        for (int m = 0; m < 2; ++m)
          #pragma unroll
          for (int n = 0; n < 8; ++n)
            acc[m][n] = __builtin_amdgcn_mfma_f32_16x16x32_bf16(af[m][c4 * 2 + kk], bf[n], acc[m][n], 0, 0, 0);
      }
    }

    // epilogue: a = (sig*mask + I)*di*dj -> bf16 LDS tile ONLY (no global stores here)
    float dj[8];
    #pragma unroll
    for (int n = 0; n < 8; ++n) dj[n] = dd[j0 + n * 16 + lr];
    #pragma unroll
    for (int m = 0; m < 2; ++m) {
      #pragma unroll
      for (int r = 0; r < 4; ++r) {
        int rl = w * 32 + m * 16 + lg * 4 + r;
        int gi = i0 + rl;
        unsigned mw = mbt32[rl][lr & 3];
        #pragma unroll
        for (int n = 0; n < 8; ++n) {
          int gj = j0 + n * 16 + lr;
          float ms = ((mw >> (n * 4 + (lr >> 2))) & 1u) ? 1.f : 0.f;
          float v = sig_clip(acc[m][n][r]) * ms + (gi == gj ? 1.f : 0.f);
          float a = v * di[m][r] * dj[n];
          lVb[rl * VP + n * 16 + lr] = f2bf(a);
        }
      }
    }
    LGKM_BAR();   // lVb visible to all

    // coalesced Ahat store pass: 512 B contiguous per row
    #pragma unroll
    for (int pass = 0; pass < 8; ++pass) {
      int row = pass * 16 + (t >> 4);
      int cc = (t & 15) * 8;
      u16x8 vv = *(const u16x8*)&lVb[row * VP + cc];
      f32x4 o0, o1;
      o0[0] = bf2f(vv[0]); o0[1] = bf2f(vv[1]); o0[2] = bf2f(vv[2]); o0[3] = bf2f(vv[3]);
      o1[0] = bf2f(vv[4]); o1[1] = bf2f(vv[5]); o1[2] = bf2f(vv[6]); o1[3] = bf2f(vv[7]);
      size_t idx = (size_t)(i0 + row) * N + j0 + cc;
      *(f32x4*)&Ahat[idx] = o0;
      *(f32x4*)&Ahat[idx + 4] = o1;
    }

    // PV: acc2 += Ahat_tile @ M2
    #pragma unroll
    for (int kk2 = 0; kk2 < 4; ++kk2) {
      short8 af2[2], bfr[4];
      #pragma unroll
      for (int m = 0; m < 2; ++m)
        af2[m] = *(const short8*)&lVb[(w * 32 + m * 16 + lr) * VP + kk2 * 32 + lg * 8];
      #pragma unroll
      for (int n = 0; n < 4; ++n)
        bfr[n] = *(const short8*)&M2T[(size_t)(n * 16 + lr) * N + j0 + kk2 * 32 + lg * 8];
      #pragma unroll
      for (int m = 0; m < 2; ++m)
        #pragma unroll
        for (int n = 0; n < 4; ++n)
          acc2[m][n] = __builtin_amdgcn_mfma_f32_16x16x32_bf16(af2[m], bfr[n], acc2[m][n], 0, 0, 0);
    }

    // next tile's mask (mbt32 reads for this tile completed before LGKM_BAR)
    if (jtl < 3) {
      int nj0 = (jq * 4 + jtl + 1) * 128;
      int mrow = t >> 1, ep = (t & 1) * 2;
      u64x2 mv = *(const u64x2*)&Mb[(size_t)(i0 + mrow) * (N / 64) + (nj0 >> 8) * 4 + ep];
      int sh = (nj0 & 128) ? 32 : 0;
      mbt32[mrow][ep] = (unsigned)(mv[0] >> sh);
      mbt32[mrow][ep + 1] = (unsigned)(mv[1] >> sh);
    }
  }

  // out partials: 16 bands per i-tile -> atomic accumulation
  #pragma unroll
  for (int m = 0; m < 2; ++m)
    #pragma unroll
    for (int n = 0; n < 4; ++n)
      #pragma unroll
      for (int r = 0; r < 4; ++r) {
        int gi = i0 + w * 32 + m * 16 + lg * 4 + r;
        int gc = n * 16 + lr;
        atomicAdd(&out[(size_t)gi * DOUT + gc], acc2[m][n][r]);
      }
}

// ---------------- K5: LeakyReLU on out ----------------
__global__ void leaky(float* out) {
  int i = blockIdx.x * 256 + threadIdx.x;
  if (i < N * DOUT) {
    float x = out[i];
    out[i] = x >= 0.f ? x : 0.01f * x;
  }
}

extern "C" void kernel_launch(void* const* d_in, const int* in_sizes, int n_in,
                              void* d_out, int out_size, void* d_ws, size_t ws_size,
                              hipStream_t stream) {
  const float* H   = (const float*)d_in[0];
  const float* A   = (const float*)d_in[1];
  const float* bnw = (const float*)d_in[2];
  const float* bnb = (const float*)d_in[3];
  const float* Wt  = (const float*)d_in[4];
  const float* bt  = (const float*)d_in[5];
  const float* Wo  = (const float*)d_in[6];
  const float* bo  = (const float*)d_in[7];
  float* out = (float*)d_out;
  float* Ahat = out + (size_t)N * DOUT;

  char* ws = (char*)d_ws;
  float* scale  = (float*)(ws + 0);
  float* shift  = (float*)(ws + 512);
  float* rowsum = (float*)(ws + 4096);                    // becomes d after dfin
  unsigned short* M2T = (unsigned short*)(ws + 65536);    // 1 MB slot [64][N]
  unsigned short* Hx  = (unsigned short*)(ws + 2097152);  // 4 MB slot
  unsigned long long* Mb = (unsigned long long*)(ws + (size_t)(6u << 20));  // 8 MB bitmask

  hipMemsetAsync(rowsum, 0, N * sizeof(float), stream);
  hipMemsetAsync(out, 0, (size_t)N * DOUT * sizeof(float), stream);

  maskpack<<<4096, 256, 0, stream>>>(A, Mb);
  bn_stats<<<DIN, 256, 0, stream>>>(H, bnw, bnb, scale, shift);
  proj<<<N / 8, 256, 0, stream>>>(H, scale, shift, Wt, bt, Wo, bo, Hx, M2T);
  rsum<<<512, 256, 0, stream>>>(Hx, Mb, rowsum);
  dfin<<<N / 256, 256, 0, stream>>>(rowsum);
  finmm<<<1024, 256, 0, stream>>>(Hx, Mb, rowsum, M2T, Ahat, out);
  leaky<<<(N * DOUT + 255) / 256, 256, 0, stream>>>(out);
}

// Round 12
// 369.864 us; speedup vs baseline: 1.1366x; 1.1366x over previous
//
#include <hip/hip_runtime.h>
#include <hip/hip_bf16.h>

#define N 8192
#define DIN 128
#define DHID 256
#define DOUT 64
#define VP 136   // LDS row stride (ushorts) for the 128-wide PV tile

typedef __attribute__((ext_vector_type(8))) short short8;
typedef __attribute__((ext_vector_type(8))) unsigned short u16x8;
typedef __attribute__((ext_vector_type(4))) float f32x4;
typedef __attribute__((ext_vector_type(2))) unsigned long long u64x2;

typedef __attribute__((address_space(1))) const unsigned int GlbU32;
typedef __attribute__((address_space(3))) unsigned int LdsU32;

__device__ inline void gload16(const void* g, void* l) {
  __builtin_amdgcn_global_load_lds((GlbU32*)g, (LdsU32*)l, 16, 0, 0);
}

// lgkmcnt-only barrier: LDS ordering without draining vmcnt (global stores keep flying)
#define LGKM_BAR()                                            \
  do {                                                        \
    asm volatile("s_waitcnt lgkmcnt(0)" ::: "memory");        \
    __builtin_amdgcn_sched_barrier(0);                        \
    __builtin_amdgcn_s_barrier();                             \
    __builtin_amdgcn_sched_barrier(0);                        \
  } while (0)

__device__ inline unsigned short f2bf(float x) {
  unsigned u = __float_as_uint(x);
  u += 0x7FFF + ((u >> 16) & 1);   // RNE
  return (unsigned short)(u >> 16);
}
__device__ inline float bf2f(unsigned short u) {
  return __uint_as_float(((unsigned)u) << 16);
}
__device__ inline float sig_clip(float x) {
  float s = 1.0f / (1.0f + __expf(-x));
  return fmaxf(s, 0.1f);
}

// ---------------- K0: pack (A>0) into interleaved bitmask, 8 MB ----------------
__global__ __launch_bounds__(256) void maskpack(const float* __restrict__ A,
                                                unsigned long long* __restrict__ Mb) {
  size_t i = (size_t)blockIdx.x * 256 + threadIdx.x;
  size_t step = (size_t)gridDim.x * 256;
  int l = threadIdx.x & 63;
  for (; i < (size_t)N * N / 4; i += step) {
    f32x4 a = *(const f32x4*)&A[i * 4];
    unsigned long long b0 = __ballot(a[0] > 0.f);
    unsigned long long b1 = __ballot(a[1] > 0.f);
    unsigned long long b2 = __ballot(a[2] > 0.f);
    unsigned long long b3 = __ballot(a[3] > 0.f);
    size_t g = (i - l) >> 6;
    if (l < 4) {
      unsigned long long bb = (l == 0) ? b0 : (l == 1) ? b1 : (l == 2) ? b2 : b3;
      Mb[g * 4 + l] = bb;
    }
  }
}

// ---------------- K1: BatchNorm statistics ----------------
__global__ void bn_stats(const float* __restrict__ H, const float* __restrict__ bnw,
                         const float* __restrict__ bnb, float* __restrict__ scale,
                         float* __restrict__ shift) {
  int f = blockIdx.x;
  int t = threadIdx.x;
  float s = 0.f, sq = 0.f;
  for (int r = t; r < N; r += 256) {
    float v = H[(size_t)r * DIN + f];
    s += v; sq += v * v;
  }
  __shared__ float ss[256], s2[256];
  ss[t] = s; s2[t] = sq;
  __syncthreads();
  for (int o = 128; o > 0; o >>= 1) {
    if (t < o) { ss[t] += ss[t + o]; s2[t] += s2[t + o]; }
    __syncthreads();
  }
  if (t == 0) {
    float mean = ss[0] * (1.0f / N);
    float var = s2[0] * (1.0f / N) - mean * mean;
    float sc = rsqrtf(var + 1e-5f) * bnw[f];
    scale[f] = sc;
    shift[f] = bnb[f] - mean * sc;
  }
}

// ---------------- K2: Hn -> Hx bf16 [N,256], M2T bf16 [64][N] ----------------
__global__ __launch_bounds__(256) void proj(const float* __restrict__ H,
                     const float* __restrict__ scale, const float* __restrict__ shift,
                     const float* __restrict__ Wt, const float* __restrict__ bt,
                     const float* __restrict__ Wo, const float* __restrict__ bo,
                     unsigned short* __restrict__ Hx, unsigned short* __restrict__ M2T) {
  __shared__ float hn[8][DIN];
  int i0 = blockIdx.x * 8;
  int t = threadIdx.x;
  #pragma unroll
  for (int rep = 0; rep < 4; ++rep) {
    int idx = rep * 256 + t;
    int r = idx >> 7, c = idx & 127;
    float h = H[(size_t)(i0 + r) * DIN + c];
    hn[r][c] = fmaf(h, scale[c], shift[c]);
  }
  __syncthreads();
  {
    int c = t;  // 0..255
    float acc[8];
    float b = bt[c];
    #pragma unroll
    for (int r = 0; r < 8; ++r) acc[r] = b;
    for (int k = 0; k < DIN; ++k) {
      float w = Wt[k * DHID + c];
      #pragma unroll
      for (int r = 0; r < 8; ++r) acc[r] = fmaf(hn[r][k], w, acc[r]);
    }
    #pragma unroll
    for (int r = 0; r < 8; ++r) Hx[(size_t)(i0 + r) * DHID + c] = f2bf(acc[r]);
  }
  if (t < DOUT) {
    int c = t;
    float acc[8];
    float b = bo[c];
    #pragma unroll
    for (int r = 0; r < 8; ++r) acc[r] = b;
    for (int k = 0; k < DIN; ++k) {
      float w = Wo[k * DOUT + c];
      #pragma unroll
      for (int r = 0; r < 8; ++r) acc[r] = fmaf(hn[r][k], w, acc[r]);
    }
    u16x8 v;
    #pragma unroll
    for (int r = 0; r < 8; ++r) v[r] = f2bf(acc[r]);
    *(u16x8*)&M2T[(size_t)c * N + i0] = v;
  }
}

// ---------------- K3: rsum — 64-row i-tile x band of 8 j-tiles, A in LDS ----------------
__global__ __launch_bounds__(256, 3) void rsum(const unsigned short* __restrict__ Hx,
                     const unsigned long long* __restrict__ Mb,
                     float* __restrict__ rowsum) {
  __shared__ unsigned short lsh[24576];   // lA [0,16384), lb [16384,24576)
  __shared__ unsigned mbt32[64][4];
  unsigned short* lA = lsh;
  unsigned short* lb = lsh + 16384;
  const int blk = blockIdx.x;
  const int jq = blk & 7;
  const int it = blk >> 3;       // 0..127
  const int i0 = it * 64;
  const int t = threadIdx.x;
  const int w = t >> 6, l = t & 63;
  const int lr = l & 15, lg = l >> 4;
  const int srow = l >> 3;
  const int scol = ((l & 7) ^ srow) * 8;
  const int fswz = (lr & 7) * 8;

  // A-init: 64x256 bf16 = 32 KB, persistent in LDS
  #pragma unroll
  for (int itr = 0; itr < 8; ++itr) {
    int idx = itr * 4 + w;              // 0..31: c4 = idx>>3, rowgroup = idx&7
    int c4 = idx >> 3, rg = idx & 7;
    int row = rg * 8 + srow;            // 0..63
    gload16(&Hx[(size_t)(i0 + row) * DHID + c4 * 64 + scol], &lA[idx * 512]);
  }
  // mask prologue (jtl=0)
  if (t < 128) {
    int j0 = jq * 1024;
    int mrow = t >> 1, ep = (t & 1) * 2;
    u64x2 mv = *(const u64x2*)&Mb[(size_t)(i0 + mrow) * (N / 64) + (j0 >> 8) * 4 + ep];
    int sh = (j0 & 128) ? 32 : 0;
    mbt32[mrow][ep] = (unsigned)(mv[0] >> sh);
    mbt32[mrow][ep + 1] = (unsigned)(mv[1] >> sh);
  }
  __syncthreads();   // drains A gloads too

  float rs[4] = {0.f, 0.f, 0.f, 0.f};
  f32x4 zero = {0.f, 0.f, 0.f, 0.f};

  for (int jtl = 0; jtl < 8; ++jtl) {
    const int j0 = (jq * 8 + jtl) * 128;
    f32x4 acc[8];
    #pragma unroll
    for (int n = 0; n < 8; ++n) acc[n] = zero;

    #pragma unroll
    for (int c4 = 0; c4 < 4; ++c4) {
      __syncthreads();
      #pragma unroll
      for (int itr = 0; itr < 4; ++itr) {
        int rg = itr * 4 + w;
        int row = rg * 8 + srow;        // 0..127 (j-rows)
        gload16(&Hx[(size_t)(j0 + row) * DHID + c4 * 64 + scol], &lb[rg * 512]);
      }
      __syncthreads();
      #pragma unroll
      for (int kk = 0; kk < 2; ++kk) {
        int c = (kk * 32 + lg * 8) ^ fswz;
        short8 a0 = *(const short8*)&lA[c4 * 4096 + (w * 16 + lr) * 64 + c];
        short8 bf[8];
        #pragma unroll
        for (int n = 0; n < 8; ++n)
          bf[n] = *(const short8*)&lb[(n * 16 + lr) * 64 + c];
        #pragma unroll
        for (int n = 0; n < 8; ++n)
          acc[n] = __builtin_amdgcn_mfma_f32_16x16x32_bf16(a0, bf[n], acc[n], 0, 0, 0);
      }
    }

    // epilogue: accumulate masked row partials (no stores)
    #pragma unroll
    for (int r = 0; r < 4; ++r) {
      int rl = w * 16 + lg * 4 + r;     // 0..63
      int gi = i0 + rl;
      unsigned mw = mbt32[rl][lr & 3];
      float part = 0.f;
      #pragma unroll
      for (int n = 0; n < 8; ++n) {
        int gj = j0 + n * 16 + lr;
        float ms = ((mw >> (n * 4 + (lr >> 2))) & 1u) ? 1.f : 0.f;
        part += sig_clip(acc[n][r]) * ms + (gi == gj ? 1.f : 0.f);
      }
      rs[r] += part;
    }
    __syncthreads();   // all mbt32 reads done before overwrite
    if (jtl < 7 && t < 128) {
      int nj0 = (jq * 8 + jtl + 1) * 128;
      int mrow = t >> 1, ep = (t & 1) * 2;
      u64x2 mv = *(const u64x2*)&Mb[(size_t)(i0 + mrow) * (N / 64) + (nj0 >> 8) * 4 + ep];
      int sh = (nj0 & 128) ? 32 : 0;
      mbt32[mrow][ep] = (unsigned)(mv[0] >> sh);
      mbt32[mrow][ep + 1] = (unsigned)(mv[1] >> sh);
    }
  }

  // one atomic set per block
  #pragma unroll
  for (int r = 0; r < 4; ++r) {
    float p = rs[r];
    p += __shfl_xor(p, 1);
    p += __shfl_xor(p, 2);
    p += __shfl_xor(p, 4);
    p += __shfl_xor(p, 8);
    if (lr == 0) atomicAdd(&rowsum[i0 + w * 16 + lg * 4 + r], p);
  }
}

// ---------------- K3b: d = rsqrt(rowsum), in place ----------------
__global__ void dfin(float* rs) {
  int i = blockIdx.x * 256 + threadIdx.x;
  if (i < N) rs[i] = rsqrtf(rs[i]);
}

// ---------------- K4: finmm — 64-row i-tile x band of 4 j-tiles, A in LDS ----------------
// Per j-tile: QK^T K-loop, epilogue (mask+sig+d scale -> bf16 LDS tile),
// coalesced Ahat f32 store pass, fused PV MFMA into acc2.
__global__ __launch_bounds__(256, 2) void finmm(const unsigned short* __restrict__ Hx,
                     const unsigned long long* __restrict__ Mb,
                     const float* __restrict__ dd,
                     const unsigned short* __restrict__ M2T,
                     float* __restrict__ Ahat, float* __restrict__ out) {
  __shared__ unsigned short lsh[33280];  // lA [0,16384), lb [16384,24576), lVb [24576,33280): [64][VP]
  __shared__ unsigned mbt32[64][4];
  unsigned short* lA = lsh;
  unsigned short* lb = lsh + 16384;
  unsigned short* lVb = lsh + 24576;
  const int blk = blockIdx.x;
  const int jq = blk & 15;               // 16 bands of 4 tiles (512 cols)
  const int it = blk >> 4;               // 0..127
  const int i0 = it * 64;
  const int t = threadIdx.x;
  const int w = t >> 6, l = t & 63;
  const int lr = l & 15, lg = l >> 4;
  const int srow = l >> 3;
  const int scol = ((l & 7) ^ srow) * 8;
  const int fswz = (lr & 7) * 8;

  // A-init: 64x256 = 32 KB persistent
  #pragma unroll
  for (int itr = 0; itr < 8; ++itr) {
    int idx = itr * 4 + w;
    int c4 = idx >> 3, rg = idx & 7;
    int row = rg * 8 + srow;
    gload16(&Hx[(size_t)(i0 + row) * DHID + c4 * 64 + scol], &lA[idx * 512]);
  }
  // mask prologue (jtl=0)
  if (t < 128) {
    int j0 = jq * 512;
    int mrow = t >> 1, ep = (t & 1) * 2;
    u64x2 mv = *(const u64x2*)&Mb[(size_t)(i0 + mrow) * (N / 64) + (j0 >> 8) * 4 + ep];
    int sh = (j0 & 128) ? 32 : 0;
    mbt32[mrow][ep] = (unsigned)(mv[0] >> sh);
    mbt32[mrow][ep + 1] = (unsigned)(mv[1] >> sh);
  }
  __syncthreads();   // drains A gloads

  float di[4];
  #pragma unroll
  for (int r = 0; r < 4; ++r) di[r] = dd[i0 + w * 16 + lg * 4 + r];

  f32x4 acc2[4];
  f32x4 zero = {0.f, 0.f, 0.f, 0.f};
  #pragma unroll
  for (int n = 0; n < 4; ++n) acc2[n] = zero;

  for (int jtl = 0; jtl < 4; ++jtl) {
    const int j0 = (jq * 4 + jtl) * 128;
    f32x4 acc[8];
    #pragma unroll
    for (int n = 0; n < 8; ++n) acc[n] = zero;

    // QK^T K-loop
    #pragma unroll
    for (int c4 = 0; c4 < 4; ++c4) {
      __syncthreads();
      #pragma unroll
      for (int itr = 0; itr < 4; ++itr) {
        int rg = itr * 4 + w;
        int row = rg * 8 + srow;        // 0..127
        gload16(&Hx[(size_t)(j0 + row) * DHID + c4 * 64 + scol], &lb[rg * 512]);
      }
      __syncthreads();
      #pragma unroll
      for (int kk = 0; kk < 2; ++kk) {
        int c = (kk * 32 + lg * 8) ^ fswz;
        short8 a0 = *(const short8*)&lA[c4 * 4096 + (w * 16 + lr) * 64 + c];
        short8 bf[8];
        #pragma unroll
        for (int n = 0; n < 8; ++n)
          bf[n] = *(const short8*)&lb[(n * 16 + lr) * 64 + c];
        #pragma unroll
        for (int n = 0; n < 8; ++n)
          acc[n] = __builtin_amdgcn_mfma_f32_16x16x32_bf16(a0, bf[n], acc[n], 0, 0, 0);
      }
    }

    // epilogue: a = (sig*mask + I)*di*dj -> bf16 LDS tile only
    float dj[8];
    #pragma unroll
    for (int n = 0; n < 8; ++n) dj[n] = dd[j0 + n * 16 + lr];
    #pragma unroll
    for (int r = 0; r < 4; ++r) {
      int rl = w * 16 + lg * 4 + r;     // 0..63
      int gi = i0 + rl;
      unsigned mw = mbt32[rl][lr & 3];
      #pragma unroll
      for (int n = 0; n < 8; ++n) {
        int gj = j0 + n * 16 + lr;
        float ms = ((mw >> (n * 4 + (lr >> 2))) & 1u) ? 1.f : 0.f;
        float v = sig_clip(acc[n][r]) * ms + (gi == gj ? 1.f : 0.f);
        float a = v * di[r] * dj[n];
        lVb[rl * VP + n * 16 + lr] = f2bf(a);
      }
    }
    LGKM_BAR();   // lVb visible; nothing vmem-drained

    // coalesced Ahat store pass: 512 B contiguous per row, 4 passes x 16 rows
    #pragma unroll
    for (int pass = 0; pass < 4; ++pass) {
      int row = pass * 16 + (t >> 4);   // 0..63
      int cc = (t & 15) * 8;
      u16x8 vv = *(const u16x8*)&lVb[row * VP + cc];
      f32x4 o0, o1;
      o0[0] = bf2f(vv[0]); o0[1] = bf2f(vv[1]); o0[2] = bf2f(vv[2]); o0[3] = bf2f(vv[3]);
      o1[0] = bf2f(vv[4]); o1[1] = bf2f(vv[5]); o1[2] = bf2f(vv[6]); o1[3] = bf2f(vv[7]);
      size_t idx = (size_t)(i0 + row) * N + j0 + cc;
      *(f32x4*)&Ahat[idx] = o0;
      *(f32x4*)&Ahat[idx + 4] = o1;
    }

    // PV: acc2 += Ahat_tile @ M2
    #pragma unroll
    for (int kk2 = 0; kk2 < 4; ++kk2) {
      short8 af2 = *(const short8*)&lVb[(w * 16 + lr) * VP + kk2 * 32 + lg * 8];
      short8 bfr[4];
      #pragma unroll
      for (int n = 0; n < 4; ++n)
        bfr[n] = *(const short8*)&M2T[(size_t)(n * 16 + lr) * N + j0 + kk2 * 32 + lg * 8];
      #pragma unroll
      for (int n = 0; n < 4; ++n)
        acc2[n] = __builtin_amdgcn_mfma_f32_16x16x32_bf16(af2, bfr[n], acc2[n], 0, 0, 0);
    }

    // next tile's mask (current epilogue reads completed before LGKM_BAR)
    if (jtl < 3 && t < 128) {
      int nj0 = (jq * 4 + jtl + 1) * 128;
      int mrow = t >> 1, ep = (t & 1) * 2;
      u64x2 mv = *(const u64x2*)&Mb[(size_t)(i0 + mrow) * (N / 64) + (nj0 >> 8) * 4 + ep];
      int sh = (nj0 & 128) ? 32 : 0;
      mbt32[mrow][ep] = (unsigned)(mv[0] >> sh);
      mbt32[mrow][ep + 1] = (unsigned)(mv[1] >> sh);
    }
  }

  // out partials: 16 bands per i-tile -> atomic accumulation
  #pragma unroll
  for (int n = 0; n < 4; ++n)
    #pragma unroll
    for (int r = 0; r < 4; ++r) {
      int gi = i0 + w * 16 + lg * 4 + r;
      int gc = n * 16 + lr;
      atomicAdd(&out[(size_t)gi * DOUT + gc], acc2[n][r]);
    }
}

// ---------------- K5: LeakyReLU on out ----------------
__global__ void leaky(float* out) {
  int i = blockIdx.x * 256 + threadIdx.x;
  if (i < N * DOUT) {
    float x = out[i];
    out[i] = x >= 0.f ? x : 0.01f * x;
  }
}

extern "C" void kernel_launch(void* const* d_in, const int* in_sizes, int n_in,
                              void* d_out, int out_size, void* d_ws, size_t ws_size,
                              hipStream_t stream) {
  const float* H   = (const float*)d_in[0];
  const float* A   = (const float*)d_in[1];
  const float* bnw = (const float*)d_in[2];
  const float* bnb = (const float*)d_in[3];
  const float* Wt  = (const float*)d_in[4];
  const float* bt  = (const float*)d_in[5];
  const float* Wo  = (const float*)d_in[6];
  const float* bo  = (const float*)d_in[7];
  float* out = (float*)d_out;
  float* Ahat = out + (size_t)N * DOUT;

  char* ws = (char*)d_ws;
  float* scale  = (float*)(ws + 0);
  float* shift  = (float*)(ws + 512);
  float* rowsum = (float*)(ws + 4096);                    // becomes d after dfin
  unsigned short* M2T = (unsigned short*)(ws + 65536);    // 1 MB slot [64][N]
  unsigned short* Hx  = (unsigned short*)(ws + 2097152);  // 4 MB slot
  unsigned long long* Mb = (unsigned long long*)(ws + (size_t)(6u << 20));  // 8 MB bitmask

  hipMemsetAsync(rowsum, 0, N * sizeof(float), stream);
  hipMemsetAsync(out, 0, (size_t)N * DOUT * sizeof(float), stream);

  maskpack<<<4096, 256, 0, stream>>>(A, Mb);
  bn_stats<<<DIN, 256, 0, stream>>>(H, bnw, bnb, scale, shift);
  proj<<<N / 8, 256, 0, stream>>>(H, scale, shift, Wt, bt, Wo, bo, Hx, M2T);
  rsum<<<1024, 256, 0, stream>>>(Hx, Mb, rowsum);
  dfin<<<N / 256, 256, 0, stream>>>(rowsum);
  finmm<<<2048, 256, 0, stream>>>(Hx, Mb, rowsum, M2T, Ahat, out);
  leaky<<<(N * DOUT + 255) / 256, 256, 0, stream>>>(out);
}